// Round 10
// baseline (568.181 us; speedup 1.0000x reference)
//
#include <hip/hip_runtime.h>

#define NN 20000
#define NE 40000
#define NGR 1000
#define KH 4                      // K-split for k_msg; pbuf stride = KH*64
#define WTF_BIAS 524288           // u16 offset of bias frags in WtF

typedef unsigned short u16;
typedef u16 u16x8 __attribute__((ext_vector_type(8)));
typedef __bf16 bf16x8 __attribute__((ext_vector_type(8)));
typedef float f32x4 __attribute__((ext_vector_type(4)));

union U8 { u16x8 u; bf16x8 b; };

__device__ __forceinline__ u16 f2bf(float f) {
    union { float f; unsigned u; } v; v.f = f;
    unsigned r = v.u + 0x7FFF + ((v.u >> 16) & 1);   // RNE
    return (u16)(r >> 16);
}
__device__ __forceinline__ float bf2f(u16 h) {
    union { unsigned u; float f; } v; v.u = ((unsigned)h) << 16;
    return v.f;
}
__device__ __forceinline__ float sigmoidf(float x) { return 1.f / (1.f + __expf(-x)); }

// ---------------- degree count ----------------
__global__ __launch_bounds__(256) void k_cnt(const int* __restrict__ ei, int* __restrict__ cnt)
{
    for (int e = blockIdx.x * 256 + threadIdx.x; e < NE; e += gridDim.x * 256)
        atomicAdd(&cnt[ei[NE + e]], 1);
}

// ---------------- exclusive prefix over cnt -> rowptr[NN+1], one block ----------
__global__ __launch_bounds__(1024) void k_scan(const int* __restrict__ cnt,
                                               int* __restrict__ rowptr)
{
    __shared__ int ps[1024];
    int t = threadIdx.x;
    int base = t * 20;
    int loc[20];
    int s = 0;
#pragma unroll
    for (int i = 0; i < 20; ++i) {
        int idx = base + i;
        loc[i] = s;
        s += (idx < NN) ? cnt[idx] : 0;
    }
    ps[t] = s;
    __syncthreads();
    for (int off = 1; off < 1024; off <<= 1) {
        int v = (t >= off) ? ps[t - off] : 0;
        __syncthreads();
        ps[t] += v;
        __syncthreads();
    }
    int ex = (t > 0) ? ps[t - 1] : 0;
#pragma unroll
    for (int i = 0; i < 20; ++i) {
        int idx = base + i;
        if (idx < NN) rowptr[idx] = ex + loc[i];
    }
    if (t == 1023) rowptr[NN] = ps[1023];
}

// -------- scatter: epos[e] = dst-sorted slot; srcs[slot] = src[e] --------------
__global__ __launch_bounds__(256) void k_scatter(const int* __restrict__ ei,
    const int* __restrict__ rowptr, int* __restrict__ cur,
    int* __restrict__ epos, int* __restrict__ srcs)
{
    for (int e = blockIdx.x * 256 + threadIdx.x; e < NE; e += gridDim.x * 256) {
        int d = ei[NE + e];
        int pos = rowptr[d] + atomicAdd(&cur[d], 1);
        epos[e] = pos;
        srcs[pos] = ei[e];
    }
}

// ============ fused one-time preamble, 992 blocks, role by blockIdx range ======
// [0,64) transposes | [64,320) lin0 | [320,832) edge_mlp(sorted) | [832,960) WtF
// [960,992) graph ranges
__global__ __launch_bounds__(256) void k_pre(
    const float* __restrict__ x, const float* __restrict__ ea,
    const int* __restrict__ batch, const int* __restrict__ epos,
    const float* __restrict__ W0, const float* __restrict__ b0,
    const float* __restrict__ We1, const float* __restrict__ be1,
    const float* __restrict__ We2, const float* __restrict__ be2,
    const float* __restrict__ W_ih, const float* __restrict__ W_hh,
    const float* __restrict__ W_ihl, const float* __restrict__ W_hhl,
    const float* __restrict__ W1,
    float* __restrict__ h, u16* __restrict__ outb, u16* __restrict__ h1,
    u16* __restrict__ WtF, int* __restrict__ gstart, int* __restrict__ gend,
    u16* __restrict__ WTg,
    float* __restrict__ WTihl, float* __restrict__ WThhl, float* __restrict__ WT1)
{
    const int b = blockIdx.x;
    const int t = threadIdx.x;

    if (b < 64) {                                    // transposes (81920 elements)
        for (int idx = b * 256 + t; idx < 81920; idx += 64 * 256) {
            int i = idx;
            if (i < 12288) { WTg[i] = f2bf(W_ih[(i % 192) * 64 + i / 192]); continue; }
            i -= 12288;
            if (i < 12288) { WTg[12288 + i] = f2bf(W_hh[(i % 192) * 64 + i / 192]); continue; }
            i -= 12288;
            if (i < 32768) { WTihl[i] = W_ihl[(i % 256) * 128 + i / 256]; continue; }
            i -= 32768;
            if (i < 16384) { WThhl[i] = W_hhl[(i % 256) * 64 + i / 256]; continue; }
            i -= 16384;
            WT1[i] = W1[(i % 64) * 128 + i / 64];
        }
        return;
    }
    if (b < 320) {                                   // lin0, 1024 waves grid-stride
        int wv = (b - 64) * 4 + (t >> 6);
        int lane = t & 63;
        float w0r[32];
#pragma unroll
        for (int f = 0; f < 32; ++f) w0r[f] = W0[lane * 32 + f];
        float b0v = b0[lane];
        for (int n = wv; n < NN; n += 1024) {
            float xv = (lane < 32) ? x[n * 32 + lane] : 0.f;
            float acc = b0v;
#pragma unroll
            for (int f = 0; f < 32; ++f) acc += __shfl(xv, f, 64) * w0r[f];
            float rv = fmaxf(acc, 0.f);
            h[n * 64 + lane] = rv;
            outb[n * 64 + lane] = f2bf(rv);
        }
        return;
    }
    if (b < 832) {                                   // edge MLP -> dst-sorted h1
        for (int idx = (b - 320) * 256 + t; idx < NE * 128; idx += 512 * 256) {
            int e = idx >> 7, k = idx & 127;
            float acc = be1[k];
#pragma unroll
            for (int j = 0; j < 5; ++j)
                acc += ea[e * 5 + j] * We1[k * 5 + j];
            h1[(size_t)epos[e] * 128 + k] = f2bf(fmaxf(acc, 0.f));
        }
        return;
    }
    if (b < 960) {                                   // WtF: frag-major B for k_msg
        for (int idx = (b - 832) * 256 + t; idx < WTF_BIAS + 4096; idx += 128 * 256) {
            float v;
            if (idx < WTF_BIAS) {
                int j = idx & 7, lane = (idx >> 3) & 63;
                int nt = (idx >> 9) & 3, s4 = (idx >> 11) & 3, ch = idx >> 13;
                int o = nt * 16 + (lane & 15);
                int k = s4 * 32 + (lane >> 4) * 8 + j;
                v = We2[(size_t)(ch * 64 + o) * 128 + k];
            } else {
                int bx = idx - WTF_BIAS;
                int j = bx & 7, lane = (bx >> 3) & 63;
                int nt = (bx >> 9) & 3, sb = bx >> 11;
                int o = nt * 16 + (lane & 15);
                int i = sb * 32 + (lane >> 4) * 8 + j;
                v = be2[i * 64 + o];
            }
            WtF[idx] = f2bf(v);
        }
        return;
    }
    {                                                // graph ranges (batch sorted)
        for (int idx = (b - 960) * 256 + t; idx < NN; idx += 32 * 256) {
            int bg = batch[idx];
            if (idx == 0 || batch[idx - 1] != bg) gstart[bg] = idx;
            if (idx == NN - 1 || batch[idx + 1] != bg) gend[bg] = idx + 1;
        }
    }
}

// ---------------- message GEMM: depth-2 pipelined B ring, barrier-free K-loop ---
// 4-buffer ring B[s4]: every MFMA group consumes a load issued ~2 groups earlier.
__global__ __launch_bounds__(256, 2) void k_msg(
    const u16* __restrict__ outb, const u16* __restrict__ h1,
    const u16* __restrict__ WtF, const int* __restrict__ srcs,
    u16* __restrict__ pbuf)
{
    __shared__ __align__(8) u16 svT[64 * 260];   // sv transposed, pad 260
    const int t = threadIdx.x;
    const int eb0 = blockIdx.x * 256;
    const int kh = blockIdx.y;                   // 0..KH-1

#pragma unroll
    for (int r = 0; r < 8; ++r) {                // gather out[srcs] -> svT
        int cid = t + 256 * r;
        int row = cid >> 3, c8 = cid & 7;
        int e = eb0 + row;
        u16x8 v = {};
        if (e < NE) { int s = srcs[e]; v = *(const u16x8*)(outb + (size_t)s * 64 + c8 * 8); }
#pragma unroll
        for (int j = 0; j < 8; ++j)
            svT[(c8 * 8 + j) * 260 + row] = v[j];
    }

    const int lane = t & 63, w = t >> 6, r16 = lane & 15, q = lane >> 4;
    const int w64 = w * 64;

    // static A-fragments: h1 rows, reused across all chunks
    u16x8 h1r[4][4];
#pragma unroll
    for (int sub = 0; sub < 4; ++sub) {
        int e = eb0 + w64 + sub * 16 + r16;
        if (e >= NE) e = NE - 1;                 // contribution zeroed via sv=0
        const u16* hp = h1 + (size_t)e * 128 + q * 8;
#pragma unroll
        for (int s4 = 0; s4 < 4; ++s4)
            h1r[sub][s4] = *(const u16x8*)(hp + s4 * 32);
    }

    f32x4 acc[4][4];
    f32x4 P[4][4];
    const f32x4 z4 = {0.f, 0.f, 0.f, 0.f};
#pragma unroll
    for (int sub = 0; sub < 4; ++sub)
#pragma unroll
        for (int nt = 0; nt < 4; ++nt) acc[sub][nt] = z4;

    U8 B0[4], B1[4], B2[4], B3[4];
    auto LD = [&](U8* dst, int ch, int s4) {
        const u16* p = WtF + (size_t)ch * 8192 + s4 * 2048 + lane * 8;
#pragma unroll
        for (int nt = 0; nt < 4; ++nt)
            dst[nt].u = *(const u16x8*)(p + nt * 512);
    };
    auto MF0 = [&](U8* bv, int s4) {
#pragma unroll
        for (int sub = 0; sub < 4; ++sub) {
            U8 a; a.u = h1r[sub][s4];
#pragma unroll
            for (int nt = 0; nt < 4; ++nt)
                P[sub][nt] = __builtin_amdgcn_mfma_f32_16x16x32_bf16(
                    a.b, bv[nt].b, z4, 0, 0, 0);
        }
    };
    auto MF = [&](U8* bv, int s4) {
#pragma unroll
        for (int sub = 0; sub < 4; ++sub) {
            U8 a; a.u = h1r[sub][s4];
#pragma unroll
            for (int nt = 0; nt < 4; ++nt)
                P[sub][nt] = __builtin_amdgcn_mfma_f32_16x16x32_bf16(
                    a.b, bv[nt].b, P[sub][nt], 0, 0, 0);
        }
    };

    __syncthreads();                             // the ONLY barrier
    LD(B0, kh * 16, 0);
    LD(B1, kh * 16, 1);

#pragma unroll 1
    for (int cc = 0; cc < 16; ++cc) {
        const int ch = kh * 16 + cc;
        LD(B2, ch, 2);
        MF0(B0, 0);                              // load issued >=2 groups ago
        LD(B3, ch, 3);
        MF(B1, 1);
        if (cc < 15) LD(B0, ch + 1, 0);
        MF(B2, 2);
        if (cc < 15) LD(B1, ch + 1, 1);
        MF(B3, 3);

        // scale by sv: one b64 read per sub
#pragma unroll
        for (int sub = 0; sub < 4; ++sub) {
            int mb = w64 + sub * 16 + q * 4;
            uint2 rv = *(const uint2*)&svT[ch * 260 + mb];
            union { unsigned u; float f; } c0, c1, c2, c3;
            c0.u = rv.x << 16; c1.u = rv.x & 0xffff0000u;
            c2.u = rv.y << 16; c3.u = rv.y & 0xffff0000u;
#pragma unroll
            for (int nt = 0; nt < 4; ++nt) {
                acc[sub][nt][0] += c0.f * P[sub][nt][0];
                acc[sub][nt][1] += c1.f * P[sub][nt][1];
                acc[sub][nt][2] += c2.f * P[sub][nt][2];
                acc[sub][nt][3] += c3.f * P[sub][nt][3];
            }
        }
    }

    if (kh == KH - 1) {   // bias block: A = out[src] rows (from svT), B = be2 frags
        U8 bvb[2][4];
#pragma unroll
        for (int sb = 0; sb < 2; ++sb)
#pragma unroll
            for (int nt = 0; nt < 4; ++nt)
                bvb[sb][nt].u = *(const u16x8*)(WtF + WTF_BIAS + ((sb * 4 + nt) * 64 + lane) * 8);
#pragma unroll
        for (int sub = 0; sub < 4; ++sub) {
            int m = w64 + sub * 16 + r16;
#pragma unroll
            for (int sb = 0; sb < 2; ++sb) {
                U8 a;
#pragma unroll
                for (int j = 0; j < 8; ++j)
                    a.u[j] = svT[(sb * 32 + q * 8 + j) * 260 + m];
#pragma unroll
                for (int nt = 0; nt < 4; ++nt)
                    acc[sub][nt] = __builtin_amdgcn_mfma_f32_16x16x32_bf16(
                        a.b, bvb[sb][nt].b, acc[sub][nt], 0, 0, 0);
            }
        }
    }

    // bf16 stores: pbuf[slot][kh][o]
#pragma unroll
    for (int sub = 0; sub < 4; ++sub) {
#pragma unroll
        for (int r = 0; r < 4; ++r) {
            int e = eb0 + w64 + sub * 16 + q * 4 + r;
            if (e >= NE) continue;
            u16* pp = pbuf + (size_t)e * (KH * 64) + kh * 64 + r16;
#pragma unroll
            for (int nt = 0; nt < 4; ++nt)
                pp[nt * 16] = f2bf(acc[sub][nt][r]);
        }
    }
}

// -------- GRU: LDS-staged bf16 weights + streaming aggregation, 8 nodes/wave ----
__global__ __launch_bounds__(256) void k_gru(float* __restrict__ h, u16* __restrict__ outb,
    const u16* __restrict__ pbuf, const int* __restrict__ rowptr,
    const float* __restrict__ b_conv, const u16* __restrict__ WTg,
    const float* __restrict__ b_ih, const float* __restrict__ b_hh)
{
    __shared__ u16 sW[24576];                    // [0,12288) W_ih^T, [12288,..) W_hh^T
    const int t = threadIdx.x;
    for (int i = t; i < 3072; i += 256)          // 24576 u16 as u16x8 chunks
        ((u16x8*)sW)[i] = ((const u16x8*)WTg)[i];
    __syncthreads();

    int wid = blockIdx.x * 4 + (t >> 6);
    int lane = t & 63;
    int n0 = wid * 8;
    if (n0 >= NN) return;
    float bcv = b_conv[lane];
    float m[8], hv[8];
    int rs = rowptr[n0];
#pragma unroll
    for (int p = 0; p < 8; ++p) {
        int n = n0 + p;
        int re = rowptr[n + 1];
        float v = 0.f;
        const u16* pb = pbuf + (size_t)rs * (KH * 64);
        for (int j = rs; j < re; ++j) {          // contiguous 512B rows
            v += bf2f(pb[lane]) + bf2f(pb[64 + lane])
               + bf2f(pb[128 + lane]) + bf2f(pb[192 + lane]);
            pb += KH * 64;
        }
        float invd = 1.f / fmaxf((float)(re - rs), 1.f);
        m[p] = fmaxf(v * invd + bcv, 0.f);
        hv[p] = h[n * 64 + lane];
        rs = re;
    }
    float air[8] = {}, aiz[8] = {}, ain[8] = {};
    float ahr[8] = {}, ahz[8] = {}, ahn[8] = {};
#pragma unroll 4
    for (int i = 0; i < 64; ++i) {
        const u16* wi = sW + i * 192;
        const u16* wh = sW + 12288 + i * 192;
        float wir = bf2f(wi[lane]), wiz = bf2f(wi[64 + lane]), win = bf2f(wi[128 + lane]);
        float whr = bf2f(wh[lane]), whz = bf2f(wh[64 + lane]), whn = bf2f(wh[128 + lane]);
#pragma unroll
        for (int p = 0; p < 8; ++p) {
            float mi = __shfl(m[p], i, 64);
            float hi = __shfl(hv[p], i, 64);
            air[p] += mi * wir; aiz[p] += mi * wiz; ain[p] += mi * win;
            ahr[p] += hi * whr; ahz[p] += hi * whz; ahn[p] += hi * whn;
        }
    }
    float bir = b_ih[lane], biz = b_ih[64 + lane], bin = b_ih[128 + lane];
    float bhr = b_hh[lane], bhz = b_hh[64 + lane], bhn = b_hh[128 + lane];
#pragma unroll
    for (int p = 0; p < 8; ++p) {
        float r = sigmoidf(air[p] + bir + ahr[p] + bhr);
        float z = sigmoidf(aiz[p] + biz + ahz[p] + bhz);
        float nng = tanhf(ain[p] + bin + r * (ahn[p] + bhn));
        float hnew = (1.f - z) * nng + z * hv[p];
        h[(n0 + p) * 64 + lane] = hnew;
        outb[(n0 + p) * 64 + lane] = f2bf(hnew);
    }
}

// -------- fused Set2Set: 1 graph per block, 3x(LSTM + attention) + readout ------
__global__ __launch_bounds__(256) void k_s2s(const float* __restrict__ h,
    const int* __restrict__ gstart, const int* __restrict__ gend,
    const float* __restrict__ WTihl, const float* __restrict__ WThhl,
    const float* __restrict__ b_ihl, const float* __restrict__ b_hhl,
    const float* __restrict__ WT1, const float* __restrict__ b1,
    const float* __restrict__ W2, const float* __restrict__ b2,
    float* __restrict__ outp)
{
    __shared__ float qs[128];        // q_star for this graph
    __shared__ float hlL[64], clL[64];
    __shared__ float gt[256];
    __shared__ float sm[4], sl[4], sr[4][64];
    const int g = blockIdx.x;
    const int t = threadIdx.x, w = t >> 6, lane = t & 63;
    const int s = gstart[g], e = gend[g];

    if (t < 128) qs[t] = 0.f;
    if (t < 64) { hlL[t] = 0.f; clL[t] = 0.f; }
    __syncthreads();

    for (int step = 0; step < 3; ++step) {
        float ga = b_ihl[t] + b_hhl[t];
#pragma unroll 4
        for (int j = 0; j < 128; ++j)
            ga += qs[j] * WTihl[j * 256 + t];
#pragma unroll 4
        for (int j = 0; j < 64; ++j)
            ga += hlL[j] * WThhl[j * 256 + t];
        gt[t] = ga;
        __syncthreads();
        if (t < 64) {
            float cv = sigmoidf(gt[64 + t]) * clL[t] + sigmoidf(gt[t]) * tanhf(gt[128 + t]);
            float hn = sigmoidf(gt[192 + t]) * tanhf(cv);
            clL[t] = cv; hlL[t] = hn; qs[t] = hn;
        }
        __syncthreads();
        float qv = hlL[lane];
        float M = -3.4e38f, l = 0.f, r = 0.f;
        for (int n = s + w; n < e; n += 4) {
            float hvv = h[n * 64 + lane];
            float p = hvv * qv;
#pragma unroll
            for (int off = 32; off > 0; off >>= 1) p += __shfl_xor(p, off, 64);
            if (p > M) {
                float sc = __expf(M - p);
                l = l * sc + 1.f;
                r = r * sc + hvv;
                M = p;
            } else {
                float pe = __expf(p - M);
                l += pe;
                r += pe * hvv;
            }
        }
        if (lane == 0) { sm[w] = M; sl[w] = l; }
        sr[w][lane] = r;
        __syncthreads();
        if (w == 0) {
            float Mg = fmaxf(fmaxf(sm[0], sm[1]), fmaxf(sm[2], sm[3]));
            float lg = 0.f, rg = 0.f;
#pragma unroll
            for (int wp = 0; wp < 4; ++wp) {
                float sc = __expf(sm[wp] - Mg);
                lg += sl[wp] * sc;
                rg += sr[wp][lane] * sc;
            }
            float inv = (lg > 0.f) ? 1.f / lg : 0.f;
            qs[64 + lane] = rg * inv;
        }
        __syncthreads();
    }
    float acc = 0.f;
#pragma unroll 4
    for (int j = w * 32; j < w * 32 + 32; ++j)
        acc += qs[j] * WT1[j * 64 + lane];
    sr[w][lane] = acc;
    __syncthreads();
    if (w == 0) {
        float y = sr[0][lane] + sr[1][lane] + sr[2][lane] + sr[3][lane] + b1[lane];
        float pr = fmaxf(y, 0.f) * W2[lane];
#pragma unroll
        for (int off = 32; off > 0; off >>= 1) pr += __shfl_xor(pr, off, 64);
        if (lane == 0) outp[g] = pr + b2[0];
    }
}

extern "C" void kernel_launch(void* const* d_in, const int* in_sizes, int n_in,
                              void* d_out, int out_size, void* d_ws, size_t ws_size,
                              hipStream_t stream)
{
    const float* x      = (const float*)d_in[0];
    const float* ea     = (const float*)d_in[1];
    const int*   ei     = (const int*)d_in[2];
    const int*   batch  = (const int*)d_in[3];
    const float* W0     = (const float*)d_in[4];
    const float* b0     = (const float*)d_in[5];
    const float* We1    = (const float*)d_in[6];
    const float* be1    = (const float*)d_in[7];
    const float* We2    = (const float*)d_in[8];
    const float* be2    = (const float*)d_in[9];
    const float* b_conv = (const float*)d_in[10];
    const float* W_ih   = (const float*)d_in[11];
    const float* W_hh   = (const float*)d_in[12];
    const float* b_ih   = (const float*)d_in[13];
    const float* b_hh   = (const float*)d_in[14];
    const float* W_ihl  = (const float*)d_in[15];
    const float* W_hhl  = (const float*)d_in[16];
    const float* b_ihl  = (const float*)d_in[17];
    const float* b_hhl  = (const float*)d_in[18];
    const float* W1     = (const float*)d_in[19];
    const float* b1     = (const float*)d_in[20];
    const float* W2     = (const float*)d_in[21];
    const float* b2     = (const float*)d_in[22];
    float* outp = (float*)d_out;

    char* ws = (char*)d_ws;
    size_t off = 0;
    auto alloc = [&](size_t bytes) -> char* {
        char* p = ws + off;
        off += (bytes + 255) & ~(size_t)255;
        return p;
    };
    u16*   h1     = (u16*)  alloc((size_t)NE * 128 * 2);       // 10.24 MB (sorted)
    u16*   WtF    = (u16*)  alloc((WTF_BIAS + 4096) * 2);      // 1.06 MB
    u16*   outb   = (u16*)  alloc((size_t)NN * 64 * 2);        // 2.56 MB
    float* h      = (float*)alloc((size_t)NN * 64 * 4);        // 5.12 MB
    u16*   pbuf   = (u16*)  alloc((size_t)NE * KH * 64 * 2);   // 20.48 MB (sorted)
    int*   rowptr = (int*)  alloc((NN + 1) * 4);
    int*   epos   = (int*)  alloc(NE * 4);
    int*   srcs   = (int*)  alloc(NE * 4);
    int*   cnt    = (int*)  alloc(NN * 4);     // cnt..gend contiguous, one memset
    int*   cur    = (int*)  alloc(NN * 4);
    int*   gstart = (int*)  alloc(NGR * 4);
    int*   gend   = (int*)  alloc(NGR * 4);
    u16*   WTg    = (u16*)  alloc(24576 * 2);  // bf16 W_ih^T | W_hh^T for k_gru
    float* WTihl  = (float*)alloc(32768 * 4);
    float* WThhl  = (float*)alloc(16384 * 4);
    float* WT1    = (float*)alloc(8192 * 4);
    if (off > ws_size) return;   // ~41 MB needed

    size_t zspan = (size_t)((char*)(gend + NGR) - (char*)cnt);
    hipMemsetAsync(cnt, 0, zspan, stream);

    k_cnt<<<64, 256, 0, stream>>>(ei, cnt);
    k_scan<<<1, 1024, 0, stream>>>(cnt, rowptr);
    k_scatter<<<64, 256, 0, stream>>>(ei, rowptr, cur, epos, srcs);
    k_pre<<<992, 256, 0, stream>>>(x, ea, batch, epos, W0, b0, We1, be1, We2, be2,
                                   W_ih, W_hh, W_ihl, W_hhl, W1,
                                   h, outb, h1, WtF, gstart, gend,
                                   WTg, WTihl, WThhl, WT1);

    dim3 mgrid((NE + 255) / 256, KH, 1);
    for (int it = 0; it < 3; ++it) {
        k_msg<<<mgrid, 256, 0, stream>>>(outb, h1, WtF, srcs, pbuf);
        k_gru<<<625, 256, 0, stream>>>(h, outb, pbuf, rowptr, b_conv,
                                       WTg, b_ih, b_hh);
    }
    k_s2s<<<NGR, 256, 0, stream>>>(h, gstart, gend, WTihl, WThhl, b_ihl, b_hhl,
                                   WT1, b1, W2, b2, outp);
}

// Round 11
// 513.444 us; speedup vs baseline: 1.1066x; 1.1066x over previous
//
#include <hip/hip_runtime.h>

#define NN 20000
#define NE 40000
#define NGR 1000
#define KH 2                      // K-split for k_msg; pbuf stride = KH*64
#define WTF_BIAS 524288           // u16 offset of bias frags in WtF

typedef unsigned short u16;
typedef u16 u16x8 __attribute__((ext_vector_type(8)));
typedef __bf16 bf16x8 __attribute__((ext_vector_type(8)));
typedef float f32x4 __attribute__((ext_vector_type(4)));

union U8 { u16x8 u; bf16x8 b; };

__device__ __forceinline__ u16 f2bf(float f) {
    union { float f; unsigned u; } v; v.f = f;
    unsigned r = v.u + 0x7FFF + ((v.u >> 16) & 1);   // RNE
    return (u16)(r >> 16);
}
__device__ __forceinline__ float bf2f(u16 h) {
    union { unsigned u; float f; } v; v.u = ((unsigned)h) << 16;
    return v.f;
}
__device__ __forceinline__ float sigmoidf(float x) { return 1.f / (1.f + __expf(-x)); }

// ---------------- degree count ----------------
__global__ __launch_bounds__(256) void k_cnt(const int* __restrict__ ei, int* __restrict__ cnt)
{
    for (int e = blockIdx.x * 256 + threadIdx.x; e < NE; e += gridDim.x * 256)
        atomicAdd(&cnt[ei[NE + e]], 1);
}

// ---------------- exclusive prefix over cnt -> rowptr[NN+1], one block ----------
__global__ __launch_bounds__(1024) void k_scan(const int* __restrict__ cnt,
                                               int* __restrict__ rowptr)
{
    __shared__ int ps[1024];
    int t = threadIdx.x;
    int base = t * 20;
    int loc[20];
    int s = 0;
#pragma unroll
    for (int i = 0; i < 20; ++i) {
        int idx = base + i;
        loc[i] = s;
        s += (idx < NN) ? cnt[idx] : 0;
    }
    ps[t] = s;
    __syncthreads();
    for (int off = 1; off < 1024; off <<= 1) {
        int v = (t >= off) ? ps[t - off] : 0;
        __syncthreads();
        ps[t] += v;
        __syncthreads();
    }
    int ex = (t > 0) ? ps[t - 1] : 0;
#pragma unroll
    for (int i = 0; i < 20; ++i) {
        int idx = base + i;
        if (idx < NN) rowptr[idx] = ex + loc[i];
    }
    if (t == 1023) rowptr[NN] = ps[1023];
}

// -------- scatter: epos[e] = dst-sorted slot; srcs[slot] = src[e] --------------
__global__ __launch_bounds__(256) void k_scatter(const int* __restrict__ ei,
    const int* __restrict__ rowptr, int* __restrict__ cur,
    int* __restrict__ epos, int* __restrict__ srcs)
{
    for (int e = blockIdx.x * 256 + threadIdx.x; e < NE; e += gridDim.x * 256) {
        int d = ei[NE + e];
        int pos = rowptr[d] + atomicAdd(&cur[d], 1);
        epos[e] = pos;
        srcs[pos] = ei[e];
    }
}

// ============ fused one-time preamble, 992 blocks, role by blockIdx range ======
__global__ __launch_bounds__(256) void k_pre(
    const float* __restrict__ x, const float* __restrict__ ea,
    const int* __restrict__ batch, const int* __restrict__ epos,
    const float* __restrict__ W0, const float* __restrict__ b0,
    const float* __restrict__ We1, const float* __restrict__ be1,
    const float* __restrict__ We2, const float* __restrict__ be2,
    const float* __restrict__ W_ih, const float* __restrict__ W_hh,
    const float* __restrict__ W_ihl, const float* __restrict__ W_hhl,
    const float* __restrict__ W1,
    float* __restrict__ h, u16* __restrict__ outb, u16* __restrict__ h1,
    u16* __restrict__ WtF, int* __restrict__ gstart, int* __restrict__ gend,
    u16* __restrict__ WTg,
    float* __restrict__ WTihl, float* __restrict__ WThhl, float* __restrict__ WT1)
{
    const int b = blockIdx.x;
    const int t = threadIdx.x;

    if (b < 64) {                                    // transposes (81920 elements)
        for (int idx = b * 256 + t; idx < 81920; idx += 64 * 256) {
            int i = idx;
            if (i < 12288) { WTg[i] = f2bf(W_ih[(i % 192) * 64 + i / 192]); continue; }
            i -= 12288;
            if (i < 12288) { WTg[12288 + i] = f2bf(W_hh[(i % 192) * 64 + i / 192]); continue; }
            i -= 12288;
            if (i < 32768) { WTihl[i] = W_ihl[(i % 256) * 128 + i / 256]; continue; }
            i -= 32768;
            if (i < 16384) { WThhl[i] = W_hhl[(i % 256) * 64 + i / 256]; continue; }
            i -= 16384;
            WT1[i] = W1[(i % 64) * 128 + i / 64];
        }
        return;
    }
    if (b < 320) {                                   // lin0, 1024 waves grid-stride
        int wv = (b - 64) * 4 + (t >> 6);
        int lane = t & 63;
        float w0r[32];
#pragma unroll
        for (int f = 0; f < 32; ++f) w0r[f] = W0[lane * 32 + f];
        float b0v = b0[lane];
        for (int n = wv; n < NN; n += 1024) {
            float xv = (lane < 32) ? x[n * 32 + lane] : 0.f;
            float acc = b0v;
#pragma unroll
            for (int f = 0; f < 32; ++f) acc += __shfl(xv, f, 64) * w0r[f];
            float rv = fmaxf(acc, 0.f);
            h[n * 64 + lane] = rv;
            outb[n * 64 + lane] = f2bf(rv);
        }
        return;
    }
    if (b < 832) {                                   // edge MLP -> dst-sorted h1
        for (int idx = (b - 320) * 256 + t; idx < NE * 128; idx += 512 * 256) {
            int e = idx >> 7, k = idx & 127;
            float acc = be1[k];
#pragma unroll
            for (int j = 0; j < 5; ++j)
                acc += ea[e * 5 + j] * We1[k * 5 + j];
            h1[(size_t)epos[e] * 128 + k] = f2bf(fmaxf(acc, 0.f));
        }
        return;
    }
    if (b < 960) {                                   // WtF: frag-major B for k_msg
        for (int idx = (b - 832) * 256 + t; idx < WTF_BIAS + 4096; idx += 128 * 256) {
            float v;
            if (idx < WTF_BIAS) {
                int j = idx & 7, lane = (idx >> 3) & 63;
                int nt = (idx >> 9) & 3, s4 = (idx >> 11) & 3, ch = idx >> 13;
                int o = nt * 16 + (lane & 15);
                int k = s4 * 32 + (lane >> 4) * 8 + j;
                v = We2[(size_t)(ch * 64 + o) * 128 + k];
            } else {
                int bx = idx - WTF_BIAS;
                int j = bx & 7, lane = (bx >> 3) & 63;
                int nt = (bx >> 9) & 3, sb = bx >> 11;
                int o = nt * 16 + (lane & 15);
                int i = sb * 32 + (lane >> 4) * 8 + j;
                v = be2[i * 64 + o];
            }
            WtF[idx] = f2bf(v);
        }
        return;
    }
    {                                                // graph ranges (batch sorted)
        for (int idx = (b - 960) * 256 + t; idx < NN; idx += 32 * 256) {
            int bg = batch[idx];
            if (idx == 0 || batch[idx - 1] != bg) gstart[bg] = idx;
            if (idx == NN - 1 || batch[idx + 1] != bg) gend[bg] = idx + 1;
        }
    }
}

// ---------------- message GEMM: depth-1 pipelined B (r9-proven), KH=2 -----------
__global__ __launch_bounds__(256, 2) void k_msg(
    const u16* __restrict__ outb, const u16* __restrict__ h1,
    const u16* __restrict__ WtF, const int* __restrict__ srcs,
    u16* __restrict__ pbuf)
{
    __shared__ __align__(8) u16 svT[64 * 260];   // sv transposed, pad 260
    const int t = threadIdx.x;
    const int eb0 = blockIdx.x * 256;
    const int kh = blockIdx.y;                   // 0..KH-1

#pragma unroll
    for (int r = 0; r < 8; ++r) {                // gather out[srcs] -> svT
        int cid = t + 256 * r;
        int row = cid >> 3, c8 = cid & 7;
        int e = eb0 + row;
        u16x8 v = {};
        if (e < NE) { int s = srcs[e]; v = *(const u16x8*)(outb + (size_t)s * 64 + c8 * 8); }
#pragma unroll
        for (int j = 0; j < 8; ++j)
            svT[(c8 * 8 + j) * 260 + row] = v[j];
    }

    const int lane = t & 63, w = t >> 6, r16 = lane & 15, q = lane >> 4;
    const int w64 = w * 64;

    // static A-fragments: h1 rows, reused across all chunks
    u16x8 h1r[4][4];
#pragma unroll
    for (int sub = 0; sub < 4; ++sub) {
        int e = eb0 + w64 + sub * 16 + r16;
        if (e >= NE) e = NE - 1;                 // contribution zeroed via sv=0
        const u16* hp = h1 + (size_t)e * 128 + q * 8;
#pragma unroll
        for (int s4 = 0; s4 < 4; ++s4)
            h1r[sub][s4] = *(const u16x8*)(hp + s4 * 32);
    }

    f32x4 acc[4][4];
    f32x4 P[4][4];
    const f32x4 z4 = {0.f, 0.f, 0.f, 0.f};
#pragma unroll
    for (int sub = 0; sub < 4; ++sub)
#pragma unroll
        for (int nt = 0; nt < 4; ++nt) acc[sub][nt] = z4;

    U8 bA[4], bB[4];
    auto LD = [&](U8* dst, int ch, int s4) {
        const u16* p = WtF + (size_t)ch * 8192 + s4 * 2048 + lane * 8;
#pragma unroll
        for (int nt = 0; nt < 4; ++nt)
            dst[nt].u = *(const u16x8*)(p + nt * 512);
    };
    auto MF0 = [&](U8* bv, int s4) {
#pragma unroll
        for (int sub = 0; sub < 4; ++sub) {
            U8 a; a.u = h1r[sub][s4];
#pragma unroll
            for (int nt = 0; nt < 4; ++nt)
                P[sub][nt] = __builtin_amdgcn_mfma_f32_16x16x32_bf16(
                    a.b, bv[nt].b, z4, 0, 0, 0);
        }
    };
    auto MF = [&](U8* bv, int s4) {
#pragma unroll
        for (int sub = 0; sub < 4; ++sub) {
            U8 a; a.u = h1r[sub][s4];
#pragma unroll
            for (int nt = 0; nt < 4; ++nt)
                P[sub][nt] = __builtin_amdgcn_mfma_f32_16x16x32_bf16(
                    a.b, bv[nt].b, P[sub][nt], 0, 0, 0);
        }
    };

    __syncthreads();                             // the ONLY barrier
    LD(bA, kh * 32, 0);

#pragma unroll 1
    for (int cc = 0; cc < 32; ++cc) {
        const int ch = kh * 32 + cc;
        LD(bB, ch, 1);  MF0(bA, 0);
        LD(bA, ch, 2);  MF (bB, 1);
        LD(bB, ch, 3);  MF (bA, 2);
        if (cc < 31) LD(bA, ch + 1, 0);
        MF(bB, 3);

        // scale by sv: one b64 read per sub
#pragma unroll
        for (int sub = 0; sub < 4; ++sub) {
            int mb = w64 + sub * 16 + q * 4;
            uint2 rv = *(const uint2*)&svT[ch * 260 + mb];
            union { unsigned u; float f; } c0, c1, c2, c3;
            c0.u = rv.x << 16; c1.u = rv.x & 0xffff0000u;
            c2.u = rv.y << 16; c3.u = rv.y & 0xffff0000u;
#pragma unroll
            for (int nt = 0; nt < 4; ++nt) {
                acc[sub][nt][0] += c0.f * P[sub][nt][0];
                acc[sub][nt][1] += c1.f * P[sub][nt][1];
                acc[sub][nt][2] += c2.f * P[sub][nt][2];
                acc[sub][nt][3] += c3.f * P[sub][nt][3];
            }
        }
    }

    if (kh == KH - 1) {   // bias block: A = out[src] rows (from svT), B = be2 frags
        U8 bvb[2][4];
#pragma unroll
        for (int sb = 0; sb < 2; ++sb)
#pragma unroll
            for (int nt = 0; nt < 4; ++nt)
                bvb[sb][nt].u = *(const u16x8*)(WtF + WTF_BIAS + ((sb * 4 + nt) * 64 + lane) * 8);
#pragma unroll
        for (int sub = 0; sub < 4; ++sub) {
            int m = w64 + sub * 16 + r16;
#pragma unroll
            for (int sb = 0; sb < 2; ++sb) {
                U8 a;
#pragma unroll
                for (int j = 0; j < 8; ++j)
                    a.u[j] = svT[(sb * 32 + q * 8 + j) * 260 + m];
#pragma unroll
                for (int nt = 0; nt < 4; ++nt)
                    acc[sub][nt] = __builtin_amdgcn_mfma_f32_16x16x32_bf16(
                        a.b, bvb[sb][nt].b, acc[sub][nt], 0, 0, 0);
            }
        }
    }

    // bf16 stores: pbuf[slot][kh][o]
#pragma unroll
    for (int sub = 0; sub < 4; ++sub) {
#pragma unroll
        for (int r = 0; r < 4; ++r) {
            int e = eb0 + w64 + sub * 16 + q * 4 + r;
            if (e >= NE) continue;
            u16* pp = pbuf + (size_t)e * (KH * 64) + kh * 64 + r16;
#pragma unroll
            for (int nt = 0; nt < 4; ++nt)
                pp[nt * 16] = f2bf(acc[sub][nt][r]);
        }
    }
}

// -------- GRU: LDS-staged bf16 weights + streaming aggregation, 8 nodes/wave ----
__global__ __launch_bounds__(256) void k_gru(float* __restrict__ h, u16* __restrict__ outb,
    const u16* __restrict__ pbuf, const int* __restrict__ rowptr,
    const float* __restrict__ b_conv, const u16* __restrict__ WTg,
    const float* __restrict__ b_ih, const float* __restrict__ b_hh)
{
    __shared__ u16 sW[24576];                    // [0,12288) W_ih^T, [12288,..) W_hh^T
    const int t = threadIdx.x;
    for (int i = t; i < 3072; i += 256)
        ((u16x8*)sW)[i] = ((const u16x8*)WTg)[i];
    __syncthreads();

    int wid = blockIdx.x * 4 + (t >> 6);
    int lane = t & 63;
    int n0 = wid * 8;
    if (n0 >= NN) return;
    float bcv = b_conv[lane];
    float m[8], hv[8];
    int rs = rowptr[n0];
#pragma unroll
    for (int p = 0; p < 8; ++p) {
        int n = n0 + p;
        int re = rowptr[n + 1];
        float v = 0.f;
        const u16* pb = pbuf + (size_t)rs * (KH * 64);
        for (int j = rs; j < re; ++j) {          // contiguous 256B rows
            v += bf2f(pb[lane]) + bf2f(pb[64 + lane]);
            pb += KH * 64;
        }
        float invd = 1.f / fmaxf((float)(re - rs), 1.f);
        m[p] = fmaxf(v * invd + bcv, 0.f);
        hv[p] = h[n * 64 + lane];
        rs = re;
    }
    float air[8] = {}, aiz[8] = {}, ain[8] = {};
    float ahr[8] = {}, ahz[8] = {}, ahn[8] = {};
#pragma unroll 4
    for (int i = 0; i < 64; ++i) {
        const u16* wi = sW + i * 192;
        const u16* wh = sW + 12288 + i * 192;
        float wir = bf2f(wi[lane]), wiz = bf2f(wi[64 + lane]), win = bf2f(wi[128 + lane]);
        float whr = bf2f(wh[lane]), whz = bf2f(wh[64 + lane]), whn = bf2f(wh[128 + lane]);
#pragma unroll
        for (int p = 0; p < 8; ++p) {
            float mi = __shfl(m[p], i, 64);
            float hi = __shfl(hv[p], i, 64);
            air[p] += mi * wir; aiz[p] += mi * wiz; ain[p] += mi * win;
            ahr[p] += hi * whr; ahz[p] += hi * whz; ahn[p] += hi * whn;
        }
    }
    float bir = b_ih[lane], biz = b_ih[64 + lane], bin = b_ih[128 + lane];
    float bhr = b_hh[lane], bhz = b_hh[64 + lane], bhn = b_hh[128 + lane];
#pragma unroll
    for (int p = 0; p < 8; ++p) {
        float r = sigmoidf(air[p] + bir + ahr[p] + bhr);
        float z = sigmoidf(aiz[p] + biz + ahz[p] + bhz);
        float nng = tanhf(ain[p] + bin + r * (ahn[p] + bhn));
        float hnew = (1.f - z) * nng + z * hv[p];
        h[(n0 + p) * 64 + lane] = hnew;
        outb[(n0 + p) * 64 + lane] = f2bf(hnew);
    }
}

// -------- fused Set2Set: 1 graph per block, 3x(LSTM + attention) + readout ------
__global__ __launch_bounds__(256) void k_s2s(const float* __restrict__ h,
    const int* __restrict__ gstart, const int* __restrict__ gend,
    const float* __restrict__ WTihl, const float* __restrict__ WThhl,
    const float* __restrict__ b_ihl, const float* __restrict__ b_hhl,
    const float* __restrict__ WT1, const float* __restrict__ b1,
    const float* __restrict__ W2, const float* __restrict__ b2,
    float* __restrict__ outp)
{
    __shared__ float qs[128];        // q_star for this graph
    __shared__ float hlL[64], clL[64];
    __shared__ float gt[256];
    __shared__ float sm[4], sl[4], sr[4][64];
    const int g = blockIdx.x;
    const int t = threadIdx.x, w = t >> 6, lane = t & 63;
    const int s = gstart[g], e = gend[g];

    if (t < 128) qs[t] = 0.f;
    if (t < 64) { hlL[t] = 0.f; clL[t] = 0.f; }
    __syncthreads();

    for (int step = 0; step < 3; ++step) {
        float ga = b_ihl[t] + b_hhl[t];
#pragma unroll 4
        for (int j = 0; j < 128; ++j)
            ga += qs[j] * WTihl[j * 256 + t];
#pragma unroll 4
        for (int j = 0; j < 64; ++j)
            ga += hlL[j] * WThhl[j * 256 + t];
        gt[t] = ga;
        __syncthreads();
        if (t < 64) {
            float cv = sigmoidf(gt[64 + t]) * clL[t] + sigmoidf(gt[t]) * tanhf(gt[128 + t]);
            float hn = sigmoidf(gt[192 + t]) * tanhf(cv);
            clL[t] = cv; hlL[t] = hn; qs[t] = hn;
        }
        __syncthreads();
        float qv = hlL[lane];
        float M = -3.4e38f, l = 0.f, r = 0.f;
        for (int n = s + w; n < e; n += 4) {
            float hvv = h[n * 64 + lane];
            float p = hvv * qv;
#pragma unroll
            for (int off = 32; off > 0; off >>= 1) p += __shfl_xor(p, off, 64);
            if (p > M) {
                float sc = __expf(M - p);
                l = l * sc + 1.f;
                r = r * sc + hvv;
                M = p;
            } else {
                float pe = __expf(p - M);
                l += pe;
                r += pe * hvv;
            }
        }
        if (lane == 0) { sm[w] = M; sl[w] = l; }
        sr[w][lane] = r;
        __syncthreads();
        if (w == 0) {
            float Mg = fmaxf(fmaxf(sm[0], sm[1]), fmaxf(sm[2], sm[3]));
            float lg = 0.f, rg = 0.f;
#pragma unroll
            for (int wp = 0; wp < 4; ++wp) {
                float sc = __expf(sm[wp] - Mg);
                lg += sl[wp] * sc;
                rg += sr[wp][lane] * sc;
            }
            float inv = (lg > 0.f) ? 1.f / lg : 0.f;
            qs[64 + lane] = rg * inv;
        }
        __syncthreads();
    }
    float acc = 0.f;
#pragma unroll 4
    for (int j = w * 32; j < w * 32 + 32; ++j)
        acc += qs[j] * WT1[j * 64 + lane];
    sr[w][lane] = acc;
    __syncthreads();
    if (w == 0) {
        float y = sr[0][lane] + sr[1][lane] + sr[2][lane] + sr[3][lane] + b1[lane];
        float pr = fmaxf(y, 0.f) * W2[lane];
#pragma unroll
        for (int off = 32; off > 0; off >>= 1) pr += __shfl_xor(pr, off, 64);
        if (lane == 0) outp[g] = pr + b2[0];
    }
}

extern "C" void kernel_launch(void* const* d_in, const int* in_sizes, int n_in,
                              void* d_out, int out_size, void* d_ws, size_t ws_size,
                              hipStream_t stream)
{
    const float* x      = (const float*)d_in[0];
    const float* ea     = (const float*)d_in[1];
    const int*   ei     = (const int*)d_in[2];
    const int*   batch  = (const int*)d_in[3];
    const float* W0     = (const float*)d_in[4];
    const float* b0     = (const float*)d_in[5];
    const float* We1    = (const float*)d_in[6];
    const float* be1    = (const float*)d_in[7];
    const float* We2    = (const float*)d_in[8];
    const float* be2    = (const float*)d_in[9];
    const float* b_conv = (const float*)d_in[10];
    const float* W_ih   = (const float*)d_in[11];
    const float* W_hh   = (const float*)d_in[12];
    const float* b_ih   = (const float*)d_in[13];
    const float* b_hh   = (const float*)d_in[14];
    const float* W_ihl  = (const float*)d_in[15];
    const float* W_hhl  = (const float*)d_in[16];
    const float* b_ihl  = (const float*)d_in[17];
    const float* b_hhl  = (const float*)d_in[18];
    const float* W1     = (const float*)d_in[19];
    const float* b1     = (const float*)d_in[20];
    const float* W2     = (const float*)d_in[21];
    const float* b2     = (const float*)d_in[22];
    float* outp = (float*)d_out;

    char* ws = (char*)d_ws;
    size_t off = 0;
    auto alloc = [&](size_t bytes) -> char* {
        char* p = ws + off;
        off += (bytes + 255) & ~(size_t)255;
        return p;
    };
    u16*   h1     = (u16*)  alloc((size_t)NE * 128 * 2);       // 10.24 MB (sorted)
    u16*   WtF    = (u16*)  alloc((WTF_BIAS + 4096) * 2);      // 1.06 MB
    u16*   outb   = (u16*)  alloc((size_t)NN * 64 * 2);        // 2.56 MB
    float* h      = (float*)alloc((size_t)NN * 64 * 4);        // 5.12 MB
    u16*   pbuf   = (u16*)  alloc((size_t)NE * KH * 64 * 2);   // 10.24 MB (sorted)
    int*   rowptr = (int*)  alloc((NN + 1) * 4);
    int*   epos   = (int*)  alloc(NE * 4);
    int*   srcs   = (int*)  alloc(NE * 4);
    int*   cnt    = (int*)  alloc(NN * 4);     // cnt..gend contiguous, one memset
    int*   cur    = (int*)  alloc(NN * 4);
    int*   gstart = (int*)  alloc(NGR * 4);
    int*   gend   = (int*)  alloc(NGR * 4);
    u16*   WTg    = (u16*)  alloc(24576 * 2);  // bf16 W_ih^T | W_hh^T for k_gru
    float* WTihl  = (float*)alloc(32768 * 4);
    float* WThhl  = (float*)alloc(16384 * 4);
    float* WT1    = (float*)alloc(8192 * 4);
    if (off > ws_size) return;   // ~31 MB needed

    size_t zspan = (size_t)((char*)(gend + NGR) - (char*)cnt);
    hipMemsetAsync(cnt, 0, zspan, stream);

    k_cnt<<<64, 256, 0, stream>>>(ei, cnt);
    k_scan<<<1, 1024, 0, stream>>>(cnt, rowptr);
    k_scatter<<<64, 256, 0, stream>>>(ei, rowptr, cur, epos, srcs);
    k_pre<<<992, 256, 0, stream>>>(x, ea, batch, epos, W0, b0, We1, be1, We2, be2,
                                   W_ih, W_hh, W_ihl, W_hhl, W1,
                                   h, outb, h1, WtF, gstart, gend,
                                   WTg, WTihl, WThhl, WT1);

    dim3 mgrid((NE + 255) / 256, KH, 1);
    for (int it = 0; it < 3; ++it) {
        k_msg<<<mgrid, 256, 0, stream>>>(outb, h1, WtF, srcs, pbuf);
        k_gru<<<625, 256, 0, stream>>>(h, outb, pbuf, rowptr, b_conv,
                                       WTg, b_ih, b_hh);
    }
    k_s2s<<<NGR, 256, 0, stream>>>(h, gstart, gend, WTihl, WThhl, b_ihl, b_hhl,
                                   WT1, b1, W2, b2, outp);
}

// Round 12
// 450.365 us; speedup vs baseline: 1.2616x; 1.1401x over previous
//
#include <hip/hip_runtime.h>

#define NN 20000
#define NE 40000
#define NGR 1000
#define KH 2                      // K-split for k_msg; pbuf stride = KH*64
#define WTF_BIAS 524288           // u16 offset of bias frags in WtF

typedef unsigned short u16;
typedef u16 u16x8 __attribute__((ext_vector_type(8)));
typedef __bf16 bf16x8 __attribute__((ext_vector_type(8)));
typedef float f32x4 __attribute__((ext_vector_type(4)));

union U8 { u16x8 u; bf16x8 b; };

__device__ __forceinline__ u16 f2bf(float f) {
    union { float f; unsigned u; } v; v.f = f;
    unsigned r = v.u + 0x7FFF + ((v.u >> 16) & 1);   // RNE
    return (u16)(r >> 16);
}
__device__ __forceinline__ float bf2f(u16 h) {
    union { unsigned u; float f; } v; v.u = ((unsigned)h) << 16;
    return v.f;
}
__device__ __forceinline__ float sigmoidf(float x) { return 1.f / (1.f + __expf(-x)); }

// ---------------- degree count ----------------
__global__ __launch_bounds__(256) void k_cnt(const int* __restrict__ ei, int* __restrict__ cnt)
{
    for (int e = blockIdx.x * 256 + threadIdx.x; e < NE; e += gridDim.x * 256)
        atomicAdd(&cnt[ei[NE + e]], 1);
}

// ---------------- exclusive prefix over cnt -> rowptr[NN+1], one block ----------
__global__ __launch_bounds__(1024) void k_scan(const int* __restrict__ cnt,
                                               int* __restrict__ rowptr)
{
    __shared__ int ps[1024];
    int t = threadIdx.x;
    int base = t * 20;
    int loc[20];
    int s = 0;
#pragma unroll
    for (int i = 0; i < 20; ++i) {
        int idx = base + i;
        loc[i] = s;
        s += (idx < NN) ? cnt[idx] : 0;
    }
    ps[t] = s;
    __syncthreads();
    for (int off = 1; off < 1024; off <<= 1) {
        int v = (t >= off) ? ps[t - off] : 0;
        __syncthreads();
        ps[t] += v;
        __syncthreads();
    }
    int ex = (t > 0) ? ps[t - 1] : 0;
#pragma unroll
    for (int i = 0; i < 20; ++i) {
        int idx = base + i;
        if (idx < NN) rowptr[idx] = ex + loc[i];
    }
    if (t == 1023) rowptr[NN] = ps[1023];
}

// -------- scatter: epos[e] = dst-sorted slot; srcs[slot] = src[e] --------------
__global__ __launch_bounds__(256) void k_scatter(const int* __restrict__ ei,
    const int* __restrict__ rowptr, int* __restrict__ cur,
    int* __restrict__ epos, int* __restrict__ srcs)
{
    for (int e = blockIdx.x * 256 + threadIdx.x; e < NE; e += gridDim.x * 256) {
        int d = ei[NE + e];
        int pos = rowptr[d] + atomicAdd(&cur[d], 1);
        epos[e] = pos;
        srcs[pos] = ei[e];
    }
}

// ============ fused one-time preamble, 992 blocks, role by blockIdx range ======
__global__ __launch_bounds__(256) void k_pre(
    const float* __restrict__ x, const float* __restrict__ ea,
    const int* __restrict__ batch, const int* __restrict__ epos,
    const float* __restrict__ W0, const float* __restrict__ b0,
    const float* __restrict__ We1, const float* __restrict__ be1,
    const float* __restrict__ We2, const float* __restrict__ be2,
    const float* __restrict__ W_ih, const float* __restrict__ W_hh,
    const float* __restrict__ W_ihl, const float* __restrict__ W_hhl,
    const float* __restrict__ W1,
    float* __restrict__ h, u16* __restrict__ outb, u16* __restrict__ h1,
    u16* __restrict__ WtF, int* __restrict__ gstart, int* __restrict__ gend,
    u16* __restrict__ WgF,
    float* __restrict__ WTihl, float* __restrict__ WThhl, float* __restrict__ WT1)
{
    const int b = blockIdx.x;
    const int t = threadIdx.x;

    if (b < 64) {                 // WgF frag-major GRU weights + transposes (90112)
        for (int idx = b * 256 + t; idx < 90112; idx += 64 * 256) {
            int i = idx;
            if (i < 32768) {      // WgF: [ks 0..3][nt 0..15][lane 0..63][j 0..7]
                int j = i & 7, lane = (i >> 3) & 63;
                int nt = (i >> 9) & 15, ks = i >> 13;
                int o = nt * 16 + (lane & 15);
                int k = ks * 32 + (lane >> 4) * 8 + j;
                float v;
                if (o < 128)      v = (k < 64) ? W_ih[o * 64 + k] : W_hh[o * 64 + k - 64];
                else if (o < 192) v = (k < 64) ? W_ih[o * 64 + k] : 0.f;
                else              v = (k >= 64) ? W_hh[(o - 64) * 64 + k - 64] : 0.f;
                WgF[i] = f2bf(v);
                continue;
            }
            i -= 32768;
            if (i < 32768) { WTihl[i] = W_ihl[(i % 256) * 128 + i / 256]; continue; }
            i -= 32768;
            if (i < 16384) { WThhl[i] = W_hhl[(i % 256) * 64 + i / 256]; continue; }
            i -= 16384;
            WT1[i] = W1[(i % 64) * 128 + i / 64];
        }
        return;
    }
    if (b < 320) {                                   // lin0, 1024 waves grid-stride
        int wv = (b - 64) * 4 + (t >> 6);
        int lane = t & 63;
        float w0r[32];
#pragma unroll
        for (int f = 0; f < 32; ++f) w0r[f] = W0[lane * 32 + f];
        float b0v = b0[lane];
        for (int n = wv; n < NN; n += 1024) {
            float xv = (lane < 32) ? x[n * 32 + lane] : 0.f;
            float acc = b0v;
#pragma unroll
            for (int f = 0; f < 32; ++f) acc += __shfl(xv, f, 64) * w0r[f];
            float rv = fmaxf(acc, 0.f);
            h[n * 64 + lane] = rv;
            outb[n * 64 + lane] = f2bf(rv);
        }
        return;
    }
    if (b < 832) {                                   // edge MLP -> dst-sorted h1
        for (int idx = (b - 320) * 256 + t; idx < NE * 128; idx += 512 * 256) {
            int e = idx >> 7, k = idx & 127;
            float acc = be1[k];
#pragma unroll
            for (int j = 0; j < 5; ++j)
                acc += ea[e * 5 + j] * We1[k * 5 + j];
            h1[(size_t)epos[e] * 128 + k] = f2bf(fmaxf(acc, 0.f));
        }
        return;
    }
    if (b < 960) {                                   // WtF: frag-major B for k_msg
        for (int idx = (b - 832) * 256 + t; idx < WTF_BIAS + 4096; idx += 128 * 256) {
            float v;
            if (idx < WTF_BIAS) {
                int j = idx & 7, lane = (idx >> 3) & 63;
                int nt = (idx >> 9) & 3, s4 = (idx >> 11) & 3, ch = idx >> 13;
                int o = nt * 16 + (lane & 15);
                int k = s4 * 32 + (lane >> 4) * 8 + j;
                v = We2[(size_t)(ch * 64 + o) * 128 + k];
            } else {
                int bx = idx - WTF_BIAS;
                int j = bx & 7, lane = (bx >> 3) & 63;
                int nt = (bx >> 9) & 3, sb = bx >> 11;
                int o = nt * 16 + (lane & 15);
                int i = sb * 32 + (lane >> 4) * 8 + j;
                v = be2[i * 64 + o];
            }
            WtF[idx] = f2bf(v);
        }
        return;
    }
    {                                                // graph ranges (batch sorted)
        for (int idx = (b - 960) * 256 + t; idx < NN; idx += 32 * 256) {
            int bg = batch[idx];
            if (idx == 0 || batch[idx - 1] != bg) gstart[bg] = idx;
            if (idx == NN - 1 || batch[idx + 1] != bg) gend[bg] = idx + 1;
        }
    }
}

// ---------------- message GEMM: depth-1 pipelined B (r9-proven), KH=2 -----------
__global__ __launch_bounds__(256, 2) void k_msg(
    const u16* __restrict__ outb, const u16* __restrict__ h1,
    const u16* __restrict__ WtF, const int* __restrict__ srcs,
    u16* __restrict__ pbuf)
{
    __shared__ __align__(8) u16 svT[64 * 260];   // sv transposed, pad 260
    const int t = threadIdx.x;
    const int eb0 = blockIdx.x * 256;
    const int kh = blockIdx.y;                   // 0..KH-1

#pragma unroll
    for (int r = 0; r < 8; ++r) {                // gather out[srcs] -> svT
        int cid = t + 256 * r;
        int row = cid >> 3, c8 = cid & 7;
        int e = eb0 + row;
        u16x8 v = {};
        if (e < NE) { int s = srcs[e]; v = *(const u16x8*)(outb + (size_t)s * 64 + c8 * 8); }
#pragma unroll
        for (int j = 0; j < 8; ++j)
            svT[(c8 * 8 + j) * 260 + row] = v[j];
    }

    const int lane = t & 63, w = t >> 6, r16 = lane & 15, q = lane >> 4;
    const int w64 = w * 64;

    // static A-fragments: h1 rows, reused across all chunks
    u16x8 h1r[4][4];
#pragma unroll
    for (int sub = 0; sub < 4; ++sub) {
        int e = eb0 + w64 + sub * 16 + r16;
        if (e >= NE) e = NE - 1;                 // contribution zeroed via sv=0
        const u16* hp = h1 + (size_t)e * 128 + q * 8;
#pragma unroll
        for (int s4 = 0; s4 < 4; ++s4)
            h1r[sub][s4] = *(const u16x8*)(hp + s4 * 32);
    }

    f32x4 acc[4][4];
    f32x4 P[4][4];
    const f32x4 z4 = {0.f, 0.f, 0.f, 0.f};
#pragma unroll
    for (int sub = 0; sub < 4; ++sub)
#pragma unroll
        for (int nt = 0; nt < 4; ++nt) acc[sub][nt] = z4;

    U8 bA[4], bB[4];
    auto LD = [&](U8* dst, int ch, int s4) {
        const u16* p = WtF + (size_t)ch * 8192 + s4 * 2048 + lane * 8;
#pragma unroll
        for (int nt = 0; nt < 4; ++nt)
            dst[nt].u = *(const u16x8*)(p + nt * 512);
    };
    auto MF0 = [&](U8* bv, int s4) {
#pragma unroll
        for (int sub = 0; sub < 4; ++sub) {
            U8 a; a.u = h1r[sub][s4];
#pragma unroll
            for (int nt = 0; nt < 4; ++nt)
                P[sub][nt] = __builtin_amdgcn_mfma_f32_16x16x32_bf16(
                    a.b, bv[nt].b, z4, 0, 0, 0);
        }
    };
    auto MF = [&](U8* bv, int s4) {
#pragma unroll
        for (int sub = 0; sub < 4; ++sub) {
            U8 a; a.u = h1r[sub][s4];
#pragma unroll
            for (int nt = 0; nt < 4; ++nt)
                P[sub][nt] = __builtin_amdgcn_mfma_f32_16x16x32_bf16(
                    a.b, bv[nt].b, P[sub][nt], 0, 0, 0);
        }
    };

    __syncthreads();                             // the ONLY barrier
    LD(bA, kh * 32, 0);

#pragma unroll 1
    for (int cc = 0; cc < 32; ++cc) {
        const int ch = kh * 32 + cc;
        LD(bB, ch, 1);  MF0(bA, 0);
        LD(bA, ch, 2);  MF (bB, 1);
        LD(bB, ch, 3);  MF (bA, 2);
        if (cc < 31) LD(bA, ch + 1, 0);
        MF(bB, 3);

        // scale by sv: one b64 read per sub
#pragma unroll
        for (int sub = 0; sub < 4; ++sub) {
            int mb = w64 + sub * 16 + q * 4;
            uint2 rv = *(const uint2*)&svT[ch * 260 + mb];
            union { unsigned u; float f; } c0, c1, c2, c3;
            c0.u = rv.x << 16; c1.u = rv.x & 0xffff0000u;
            c2.u = rv.y << 16; c3.u = rv.y & 0xffff0000u;
#pragma unroll
            for (int nt = 0; nt < 4; ++nt) {
                acc[sub][nt][0] += c0.f * P[sub][nt][0];
                acc[sub][nt][1] += c1.f * P[sub][nt][1];
                acc[sub][nt][2] += c2.f * P[sub][nt][2];
                acc[sub][nt][3] += c3.f * P[sub][nt][3];
            }
        }
    }

    if (kh == KH - 1) {   // bias block: A = out[src] rows (from svT), B = be2 frags
        U8 bvb[2][4];
#pragma unroll
        for (int sb = 0; sb < 2; ++sb)
#pragma unroll
            for (int nt = 0; nt < 4; ++nt)
                bvb[sb][nt].u = *(const u16x8*)(WtF + WTF_BIAS + ((sb * 4 + nt) * 64 + lane) * 8);
#pragma unroll
        for (int sub = 0; sub < 4; ++sub) {
            int m = w64 + sub * 16 + r16;
#pragma unroll
            for (int sb = 0; sb < 2; ++sb) {
                U8 a;
#pragma unroll
                for (int j = 0; j < 8; ++j)
                    a.u[j] = svT[(sb * 32 + q * 8 + j) * 260 + m];
#pragma unroll
                for (int nt = 0; nt < 4; ++nt)
                    acc[sub][nt] = __builtin_amdgcn_mfma_f32_16x16x32_bf16(
                        a.b, bvb[sb][nt].b, acc[sub][nt], 0, 0, 0);
            }
        }
    }

    // bf16 stores: pbuf[slot][kh][o]
#pragma unroll
    for (int sub = 0; sub < 4; ++sub) {
#pragma unroll
        for (int r = 0; r < 4; ++r) {
            int e = eb0 + w64 + sub * 16 + q * 4 + r;
            if (e >= NE) continue;
            u16* pp = pbuf + (size_t)e * (KH * 64) + kh * 64 + r16;
#pragma unroll
            for (int nt = 0; nt < 4; ++nt)
                pp[nt * 16] = f2bf(acc[sub][nt][r]);
        }
    }
}

// -------- GRU: streaming aggregation + MFMA gate GEMM, 64 nodes/block -----------
// C[64x256] = [m|h][64x128] @ WgF[128x256]; gate combine in C-layout registers.
__global__ __launch_bounds__(256) void k_gru(float* __restrict__ h, u16* __restrict__ outb,
    const u16* __restrict__ pbuf, const int* __restrict__ rowptr,
    const float* __restrict__ b_conv, const u16* __restrict__ WgF,
    const float* __restrict__ b_ih, const float* __restrict__ b_hh)
{
    __shared__ __align__(16) u16 zA[64 * 132];   // [m|h] bf16, row pad 132
    __shared__ float hS[64 * 65];                // old h fp32, row pad 65
    const int t = threadIdx.x;
    const int lane = t & 63, w = t >> 6, r16 = lane & 15, q = lane >> 4;
    const int n0 = blockIdx.x * 64;
    const int w16 = w * 16;
    float bcv = b_conv[lane];

    // ---- phase 1: aggregation (each wave: its 16 nodes, lane = dim) ----
#pragma unroll 1
    for (int p = 0; p < 16; ++p) {
        int n = n0 + w16 + p;
        float m = 0.f, hvv = 0.f;
        if (n < NN) {
            int rs = rowptr[n], re = rowptr[n + 1];
            float v = 0.f;
            const u16* pb = pbuf + (size_t)rs * (KH * 64);
            for (int j = rs; j < re; ++j) {
                v += bf2f(pb[lane]) + bf2f(pb[64 + lane]);
                pb += KH * 64;
            }
            m = fmaxf(v / fmaxf((float)(re - rs), 1.f) + bcv, 0.f);
            hvv = h[n * 64 + lane];
        }
        zA[(w16 + p) * 132 + lane] = f2bf(m);
        zA[(w16 + p) * 132 + 64 + lane] = f2bf(hvv);
        hS[(w16 + p) * 65 + lane] = hvv;
    }
    // wave-private LDS rows: no cross-wave dependency, no barrier needed

    // ---- phase 2: GEMM, wave computes its 16 nodes x 256 outputs ----
    u16x8 afr[4];
#pragma unroll
    for (int ks = 0; ks < 4; ++ks)
        afr[ks] = *(const u16x8*)&zA[(w16 + r16) * 132 + ks * 32 + q * 8];

    f32x4 acc[16];
    const f32x4 z4 = {0.f, 0.f, 0.f, 0.f};
#pragma unroll
    for (int nt = 0; nt < 16; ++nt) acc[nt] = z4;

    U8 bA[4], bB[4];
    auto LDB = [&](U8* dst, int nt) {
#pragma unroll
        for (int ks = 0; ks < 4; ++ks)
            dst[ks].u = *(const u16x8*)(WgF + ((ks * 16 + nt) * 64 + lane) * 8);
    };
    LDB(bA, 0);
#pragma unroll
    for (int nt = 0; nt < 16; ++nt) {
        U8* cur = (nt & 1) ? bB : bA;
        U8* nxt = (nt & 1) ? bA : bB;
        if (nt < 15) LDB(nxt, nt + 1);
        f32x4 c = acc[nt];
#pragma unroll
        for (int ks = 0; ks < 4; ++ks) {
            U8 a; a.u = afr[ks];
            c = __builtin_amdgcn_mfma_f32_16x16x32_bf16(a.b, cur[ks].b, c, 0, 0, 0);
        }
        acc[nt] = c;
    }

    // ---- phase 3: gate combine; C row = q*4+reg, col = nt*16+r16 ----
#pragma unroll
    for (int reg = 0; reg < 4; ++reg) {
        int nl = w16 + q * 4 + reg;
        int n = n0 + nl;
        if (n >= NN) continue;
#pragma unroll
        for (int dd = 0; dd < 4; ++dd) {
            int d = dd * 16 + r16;
            float rv = acc[dd][reg]      + b_ih[d]       + b_hh[d];
            float zv = acc[4 + dd][reg]  + b_ih[64 + d]  + b_hh[64 + d];
            float iv = acc[8 + dd][reg]  + b_ih[128 + d];
            float hg = acc[12 + dd][reg] + b_hh[128 + d];
            float rr = sigmoidf(rv), zz = sigmoidf(zv);
            float nn = tanhf(iv + rr * hg);
            float hold = hS[nl * 65 + d];
            float hnew = (1.f - zz) * nn + zz * hold;
            h[n * 64 + d] = hnew;
            outb[n * 64 + d] = f2bf(hnew);
        }
    }
}

// -------- fused Set2Set: 1 graph per block, 3x(LSTM + attention) + readout ------
__global__ __launch_bounds__(256) void k_s2s(const float* __restrict__ h,
    const int* __restrict__ gstart, const int* __restrict__ gend,
    const float* __restrict__ WTihl, const float* __restrict__ WThhl,
    const float* __restrict__ b_ihl, const float* __restrict__ b_hhl,
    const float* __restrict__ WT1, const float* __restrict__ b1,
    const float* __restrict__ W2, const float* __restrict__ b2,
    float* __restrict__ outp)
{
    __shared__ float qs[128];        // q_star for this graph
    __shared__ float hlL[64], clL[64];
    __shared__ float gt[256];
    __shared__ float sm[4], sl[4], sr[4][64];
    const int g = blockIdx.x;
    const int t = threadIdx.x, w = t >> 6, lane = t & 63;
    const int s = gstart[g], e = gend[g];

    if (t < 128) qs[t] = 0.f;
    if (t < 64) { hlL[t] = 0.f; clL[t] = 0.f; }
    __syncthreads();

    for (int step = 0; step < 3; ++step) {
        float ga = b_ihl[t] + b_hhl[t];
#pragma unroll 4
        for (int j = 0; j < 128; ++j)
            ga += qs[j] * WTihl[j * 256 + t];
#pragma unroll 4
        for (int j = 0; j < 64; ++j)
            ga += hlL[j] * WThhl[j * 256 + t];
        gt[t] = ga;
        __syncthreads();
        if (t < 64) {
            float cv = sigmoidf(gt[64 + t]) * clL[t] + sigmoidf(gt[t]) * tanhf(gt[128 + t]);
            float hn = sigmoidf(gt[192 + t]) * tanhf(cv);
            clL[t] = cv; hlL[t] = hn; qs[t] = hn;
        }
        __syncthreads();
        float qv = hlL[lane];
        float M = -3.4e38f, l = 0.f, r = 0.f;
        for (int n = s + w; n < e; n += 4) {
            float hvv = h[n * 64 + lane];
            float p = hvv * qv;
#pragma unroll
            for (int off = 32; off > 0; off >>= 1) p += __shfl_xor(p, off, 64);
            if (p > M) {
                float sc = __expf(M - p);
                l = l * sc + 1.f;
                r = r * sc + hvv;
                M = p;
            } else {
                float pe = __expf(p - M);
                l += pe;
                r += pe * hvv;
            }
        }
        if (lane == 0) { sm[w] = M; sl[w] = l; }
        sr[w][lane] = r;
        __syncthreads();
        if (w == 0) {
            float Mg = fmaxf(fmaxf(sm[0], sm[1]), fmaxf(sm[2], sm[3]));
            float lg = 0.f, rg = 0.f;
#pragma unroll
            for (int wp = 0; wp < 4; ++wp) {
                float sc = __expf(sm[wp] - Mg);
                lg += sl[wp] * sc;
                rg += sr[wp][lane] * sc;
            }
            float inv = (lg > 0.f) ? 1.f / lg : 0.f;
            qs[64 + lane] = rg * inv;
        }
        __syncthreads();
    }
    float acc = 0.f;
#pragma unroll 4
    for (int j = w * 32; j < w * 32 + 32; ++j)
        acc += qs[j] * WT1[j * 64 + lane];
    sr[w][lane] = acc;
    __syncthreads();
    if (w == 0) {
        float y = sr[0][lane] + sr[1][lane] + sr[2][lane] + sr[3][lane] + b1[lane];
        float pr = fmaxf(y, 0.f) * W2[lane];
#pragma unroll
        for (int off = 32; off > 0; off >>= 1) pr += __shfl_xor(pr, off, 64);
        if (lane == 0) outp[g] = pr + b2[0];
    }
}

extern "C" void kernel_launch(void* const* d_in, const int* in_sizes, int n_in,
                              void* d_out, int out_size, void* d_ws, size_t ws_size,
                              hipStream_t stream)
{
    const float* x      = (const float*)d_in[0];
    const float* ea     = (const float*)d_in[1];
    const int*   ei     = (const int*)d_in[2];
    const int*   batch  = (const int*)d_in[3];
    const float* W0     = (const float*)d_in[4];
    const float* b0     = (const float*)d_in[5];
    const float* We1    = (const float*)d_in[6];
    const float* be1    = (const float*)d_in[7];
    const float* We2    = (const float*)d_in[8];
    const float* be2    = (const float*)d_in[9];
    const float* b_conv = (const float*)d_in[10];
    const float* W_ih   = (const float*)d_in[11];
    const float* W_hh   = (const float*)d_in[12];
    const float* b_ih   = (const float*)d_in[13];
    const float* b_hh   = (const float*)d_in[14];
    const float* W_ihl  = (const float*)d_in[15];
    const float* W_hhl  = (const float*)d_in[16];
    const float* b_ihl  = (const float*)d_in[17];
    const float* b_hhl  = (const float*)d_in[18];
    const float* W1     = (const float*)d_in[19];
    const float* b1     = (const float*)d_in[20];
    const float* W2     = (const float*)d_in[21];
    const float* b2     = (const float*)d_in[22];
    float* outp = (float*)d_out;

    char* ws = (char*)d_ws;
    size_t off = 0;
    auto alloc = [&](size_t bytes) -> char* {
        char* p = ws + off;
        off += (bytes + 255) & ~(size_t)255;
        return p;
    };
    u16*   h1     = (u16*)  alloc((size_t)NE * 128 * 2);       // 10.24 MB (sorted)
    u16*   WtF    = (u16*)  alloc((WTF_BIAS + 4096) * 2);      // 1.06 MB
    u16*   outb   = (u16*)  alloc((size_t)NN * 64 * 2);        // 2.56 MB
    float* h      = (float*)alloc((size_t)NN * 64 * 4);        // 5.12 MB
    u16*   pbuf   = (u16*)  alloc((size_t)NE * KH * 64 * 2);   // 10.24 MB (sorted)
    int*   rowptr = (int*)  alloc((NN + 1) * 4);
    int*   epos   = (int*)  alloc(NE * 4);
    int*   srcs   = (int*)  alloc(NE * 4);
    int*   cnt    = (int*)  alloc(NN * 4);     // cnt..gend contiguous, one memset
    int*   cur    = (int*)  alloc(NN * 4);
    int*   gstart = (int*)  alloc(NGR * 4);
    int*   gend   = (int*)  alloc(NGR * 4);
    u16*   WgF    = (u16*)  alloc(32768 * 2);  // frag-major GRU gate weights
    float* WTihl  = (float*)alloc(32768 * 4);
    float* WThhl  = (float*)alloc(16384 * 4);
    float* WT1    = (float*)alloc(8192 * 4);
    if (off > ws_size) return;   // ~31 MB needed

    size_t zspan = (size_t)((char*)(gend + NGR) - (char*)cnt);
    hipMemsetAsync(cnt, 0, zspan, stream);

    k_cnt<<<64, 256, 0, stream>>>(ei, cnt);
    k_scan<<<1, 1024, 0, stream>>>(cnt, rowptr);
    k_scatter<<<64, 256, 0, stream>>>(ei, rowptr, cur, epos, srcs);
    k_pre<<<992, 256, 0, stream>>>(x, ea, batch, epos, W0, b0, We1, be1, We2, be2,
                                   W_ih, W_hh, W_ihl, W_hhl, W1,
                                   h, outb, h1, WtF, gstart, gend,
                                   WgF, WTihl, WThhl, WT1);

    dim3 mgrid((NE + 255) / 256, KH, 1);
    for (int it = 0; it < 3; ++it) {
        k_msg<<<mgrid, 256, 0, stream>>>(outb, h1, WtF, srcs, pbuf);
        k_gru<<<313, 256, 0, stream>>>(h, outb, pbuf, rowptr, b_conv,
                                       WgF, b_ih, b_hh);
    }
    k_s2s<<<NGR, 256, 0, stream>>>(h, gstart, gend, WTihl, WThhl, b_ihl, b_hhl,
                                   WT1, b1, W2, b2, outp);
}